// Round 11
// baseline (439.836 us; speedup 1.0000x reference)
//
#include <hip/hip_runtime.h>

// ---------------------------------------------------------------------------
// Attention (LSA, ViT-style) for MI355X / gfx950.
// B=32, N=577, DIM=768, H=12, DH=64. f16 MFMA, fp32 accumulate.
// 4 launches: prep(transposes) -> gemm_qkv(fused x-cvt) -> attn -> gemm_out.
// gemm_qkv: 128x128 tile, 4 waves, 2-buffer pipeline; A staged DIRECTLY from
//   f32 x via global->reg->cvt->ds_write (T14 split: load at iter top, cvt
//   after MFMA; counted vmcnt(6)/vmcnt(2); row-clamped loads keep the VMEM
//   count wave-uniform). B via global_load_lds. Conflict-free XOR pre-swizzle
//   (BANK_CONFLICT=0 verified); XCD-chunked bijective n-fastest grid
//   (FETCH 146->58 MB verified). cvt_x kernel deleted.
// Attn: double-buffered K/V (PREF(kt+1) before compute(kt), vmcnt(4)),
//   no-max exp2 softmax, S^T trick, register P, XCD-chunked grid.
// ---------------------------------------------------------------------------

typedef _Float16 half8  __attribute__((ext_vector_type(8)));
typedef _Float16 h4f    __attribute__((ext_vector_type(4)));
typedef __fp16   hv2    __attribute__((ext_vector_type(2)));
typedef __fp16   hv4    __attribute__((ext_vector_type(4)));
typedef float    floatx4 __attribute__((ext_vector_type(4)));

#define MTOT   18464          // B*N = 32*577
#define NEG_V  (-987654321.0f)
#define VTS    584            // padded row stride for V^T (multiple of 8)

// async 16B global->LDS (LDS dst = wave-uniform base + lane*16B)
__device__ __forceinline__ void gl_lds16(const _Float16* g, _Float16* l) {
    __builtin_amdgcn_global_load_lds(
        (const __attribute__((address_space(1))) unsigned int*)g,
        (__attribute__((address_space(3))) unsigned int*)l,
        16, 0, 0);
}

// ---------------- prep: both weight transposes in ONE launch ----------------
// src[K=768][Ncol] f32 -> dst[Ncol][768] f16.  grid (72, 48):
//   by <  24 : W_qkv (Ncol=2304), k0 = by*32,      n0 = bx*32  (bx < 72)
//   by >= 24 : W_out (Ncol= 768), k0 = (by-24)*32, n0 = bx*32  (bx < 24)
__global__ __launch_bounds__(256) void transpose_both(const float* __restrict__ Wqkv,
                                                      const float* __restrict__ Wout,
                                                      _Float16* __restrict__ WqkvT,
                                                      _Float16* __restrict__ WoutT) {
    const float* src;
    _Float16* dst;
    int Ncol, k0, n0;
    if (blockIdx.y < 24) {
        src = Wqkv; dst = WqkvT; Ncol = 2304;
        k0 = blockIdx.y * 32; n0 = blockIdx.x * 32;
    } else {
        if (blockIdx.x >= 24) return;            // block-uniform early exit
        src = Wout; dst = WoutT; Ncol = 768;
        k0 = (blockIdx.y - 24) * 32; n0 = blockIdx.x * 32;
    }
    __shared__ float tile[32][33];
    const int tx = threadIdx.x & 31, ty = threadIdx.x >> 5;   // 32 x 8
    for (int i = 0; i < 32; i += 8)
        tile[ty + i][tx] = src[(size_t)(k0 + ty + i) * Ncol + (n0 + tx)];
    __syncthreads();
    for (int i = 0; i < 32; i += 8)
        dst[(size_t)(n0 + ty + i) * 768 + (k0 + tx)] = (_Float16)tile[tx][ty + i];
}

// ---------------- GEMM1: qkv = x(f32) @ W_qkv^T, scatter to q,k,v^T ---------
// 128x128 tile, 4 waves (2x2 of 64x64), BK=32, 2-buffer pipeline.
// A-operand staged from f32 x: 4x global_load_dwordx4 at iter top ->
// cvt_pkrtz + 2x ds_write_b128 after the MFMA cluster (T14 split).
// Grid: 2610 blocks flat, XCD-chunked bijective swizzle (q=326,r=2),
// n-fastest (18 n-tiles/row) -> A-panel + W_qkvT L2-resident.
// q outputs pre-multiplied by scale[h]*log2(e) so attention uses exp2.
__global__ __launch_bounds__(256, 4) void gemm_qkv(const float* __restrict__ x,
                                                   const _Float16* __restrict__ wT,
                                                   const float* __restrict__ scale,
                                                   _Float16* __restrict__ qg,
                                                   _Float16* __restrict__ kg,
                                                   _Float16* __restrict__ vT) {
    __shared__ _Float16 As[2][128 * 32];    // 2 x 8 KB
    __shared__ _Float16 Bs[2][128 * 32];    // 2 x 8 KB   (32 KB total)
    // bijective XCD swizzle: nwg=2610, q=326, r=2
    const unsigned orig = blockIdx.x;
    const unsigned xcd = orig & 7u, bidx = orig >> 3;
    const unsigned swz = (xcd < 2u ? xcd * 327u : 654u + (xcd - 2u) * 326u) + bidx;
    const unsigned mi = swz / 18u, ni = swz - mi * 18u;
    const int m0 = (int)mi * 128, n0 = (int)ni * 128;
    const int tid = threadIdx.x;
    const int lane = tid & 63, wv = tid >> 6;        // 4 waves
    const int wrow = wv >> 1, wcol = wv & 1;         // 2 x 2
    const int lr = lane & 15, lq = lane >> 4;

    // staging geometry; chunk column pre-swizzled by row so the (linear)
    // LDS tile holds source chunk (c ^ ((row>>1)&3)) at slot c.
    const int r1 = tid >> 2,        c1 = (((tid & 3) ^ ((r1 >> 1) & 3)) * 8);
    const int r2 = 64 + (tid >> 2), c2 = (((tid & 3) ^ ((r2 >> 1) & 3)) * 8);
    // read-side swizzled chunk: (row>>1)&3 == (lr>>1)&3 for fragment rows
    const int xc = (lq ^ ((lr >> 1) & 3)) * 8;

    // A source: rows clamped to MTOT-1 (loads ALWAYS issue -> vmcnt counts
    // stay wave-uniform; clamped-row garbage never stored by the epilogue).
    const int rr1 = (m0 + r1 < MTOT) ? (m0 + r1) : (MTOT - 1);
    const int rr2 = (m0 + r2 < MTOT) ? (m0 + r2) : (MTOT - 1);
    const float* xp1 = x + (size_t)rr1 * 768 + c1;
    const float* xp2 = x + (size_t)rr2 * 768 + c2;
    // A ds_write destinations (match gl_lds16's base+lane*16B layout)
    _Float16* wd1[2] = { &As[0][wv * 512 + lane * 8], &As[1][wv * 512 + lane * 8] };
    _Float16* wd2[2] = { &As[0][2048 + wv * 512 + lane * 8], &As[1][2048 + wv * 512 + lane * 8] };

    floatx4 acc[4][4];
    const floatx4 fz = {0.f, 0.f, 0.f, 0.f};
    for (int i = 0; i < 4; ++i)
        for (int j = 0; j < 4; ++j) acc[i][j] = fz;

    float4 la0, la1, la2, la3;                       // A regs in flight
    #define A_LOAD(ki)                                                              \
        do {                                                                        \
            const int kk_ = (ki) * 32;                                              \
            la0 = *(const float4*)(xp1 + kk_);                                      \
            la1 = *(const float4*)(xp1 + kk_ + 4);                                  \
            la2 = *(const float4*)(xp2 + kk_);                                      \
            la3 = *(const float4*)(xp2 + kk_ + 4);                                  \
        } while (0)
    #define CVT_WRITE(B)                                                            \
        do {                                                                        \
            half8 h1, h2;                                                           \
            h1[0] = (_Float16)la0.x; h1[1] = (_Float16)la0.y;                       \
            h1[2] = (_Float16)la0.z; h1[3] = (_Float16)la0.w;                       \
            h1[4] = (_Float16)la1.x; h1[5] = (_Float16)la1.y;                       \
            h1[6] = (_Float16)la1.z; h1[7] = (_Float16)la1.w;                       \
            h2[0] = (_Float16)la2.x; h2[1] = (_Float16)la2.y;                       \
            h2[2] = (_Float16)la2.z; h2[3] = (_Float16)la2.w;                       \
            h2[4] = (_Float16)la3.x; h2[5] = (_Float16)la3.y;                       \
            h2[6] = (_Float16)la3.z; h2[7] = (_Float16)la3.w;                       \
            *(half8*)wd1[B] = h1;                                                   \
            *(half8*)wd2[B] = h2;                                                   \
        } while (0)
    #define B_STAGE(ki, B)                                                          \
        do {                                                                        \
            const int kk_ = (ki) * 32;                                              \
            gl_lds16(wT + (size_t)(n0 + r1) * 768 + kk_ + c1, &Bs[B][wv*64*8]);     \
            gl_lds16(wT + (size_t)(n0 + r2) * 768 + kk_ + c2,                       \
                     &Bs[B][(256 + wv*64) * 8]);                                    \
        } while (0)

    // prologue: tile 0 into buffer 0
    A_LOAD(0);
    B_STAGE(0, 0);
    asm volatile("s_waitcnt vmcnt(2)" ::: "memory");   // A(0) landed; B(0) in flight
    CVT_WRITE(0);

    for (int ki = 0; ki < 24; ++ki) {
        const int bf = ki & 1;
        if (ki < 23) {
            A_LOAD(ki + 1);
            B_STAGE(ki + 1, bf ^ 1);
            // queue: B(ki)[2] oldest, A(ki+1)[4], B(ki+1)[2]
            asm volatile("s_waitcnt vmcnt(6) lgkmcnt(0)" ::: "memory");
        } else {
            asm volatile("s_waitcnt vmcnt(0) lgkmcnt(0)" ::: "memory");
        }
        asm volatile("s_barrier" ::: "memory");

        half8 af[4], bfr[4];
        #pragma unroll
        for (int i = 0; i < 4; ++i)
            af[i] = *(const half8*)&As[bf][(wrow * 64 + i * 16 + lr) * 32 + xc];
        #pragma unroll
        for (int j = 0; j < 4; ++j)
            bfr[j] = *(const half8*)&Bs[bf][(wcol * 64 + j * 16 + lr) * 32 + xc];
        #pragma unroll
        for (int i = 0; i < 4; ++i)
            #pragma unroll
            for (int j = 0; j < 4; ++j)
                acc[i][j] = __builtin_amdgcn_mfma_f32_16x16x32_f16(af[i], bfr[j], acc[i][j], 0, 0, 0);

        if (ki < 23) {
            // A(ki+1) regs ready (only B(ki+1)[2] may remain in flight)
            asm volatile("s_waitcnt vmcnt(2)" ::: "memory");
            CVT_WRITE(bf ^ 1);
        }
        // WAR + write-drain: reads of buf bf retired, our ds_writes complete
        asm volatile("s_waitcnt lgkmcnt(0)\n\ts_barrier" ::: "memory");
    }
    #undef A_LOAD
    #undef CVT_WRITE
    #undef B_STAGE

    // epilogue: wave-uniform which/h (wave col-base is a multiple of 64)
    const int cbase = n0 + wcol * 64;
    const int which = cbase / 768;                    // 0=q 1=k 2=v
    const int h = (cbase - which * 768) >> 6;         // head (uniform)
    const float qsc = (which == 0) ? scale[h] * 1.4426950408889634f : 1.0f;
    #pragma unroll
    for (int j = 0; j < 4; ++j) {
        const int d = j * 16 + lr;                    // 0..63 within head
        #pragma unroll
        for (int i = 0; i < 4; ++i)
            #pragma unroll
            for (int r = 0; r < 4; ++r) {
                const int row = m0 + wrow * 64 + i * 16 + lq * 4 + r;
                if (row >= MTOT) continue;
                const unsigned bb = (unsigned)row / 577u;
                const unsigned nn = (unsigned)row - bb * 577u;
                const _Float16 val = (_Float16)(acc[i][j][r] * qsc);
                const size_t head = (size_t)(bb * 12 + h);
                if (which == 0)      qg[(head * 577 + nn) * 64 + d] = val;
                else if (which == 1) kg[(head * 577 + nn) * 64 + d] = val;
                else                 vT[(head * 64 + d) * VTS + nn] = val;
            }
    }
}

// ---------------- flash attention: per (b,h,qtile128) block, 4 waves --------
// Flat 1920-block grid, XCD-chunked, qt fastest (head K/V L2-resident).
// K/V double-buffered: PREF(kt+1) issued BEFORE compute(kt); counted vmcnt(4).
__global__ __launch_bounds__(256) void attn_kernel(const _Float16* __restrict__ qg,
                                                   const _Float16* __restrict__ kg,
                                                   const _Float16* __restrict__ vT,
                                                   _Float16* __restrict__ Og) {
    __shared__ __align__(16) _Float16 Ks[2][64 * 64];   // [j][d], swizzled chunks
    __shared__ __align__(16) _Float16 Vs[2][64 * 64];   // [d][j], swizzled chunks
    const unsigned orig = blockIdx.x;                 // 1920 blocks
    const unsigned swz = (orig & 7u) * 240u + (orig >> 3);
    const int qt = (int)(swz % 5u);
    const unsigned hb = swz / 5u;
    const int h = (int)(hb % 12u), b = (int)(hb / 12u);
    const int tid = threadIdx.x, lane = tid & 63, wv = tid >> 6;
    const int lr = lane & 15, lq = lane >> 4;
    const size_t head = (size_t)(b * 12 + h);
    const _Float16* qh = qg + head * 577 * 64;
    const _Float16* kh = kg + head * 577 * 64;
    const _Float16* vh = vT + head * 64 * VTS;
    const int q0 = qt * 128;
    const int xs = lq ^ (lr & 7), xs4 = xs ^ 4;      // swizzled b128 chunks

    half8 bq[2][2];
    #pragma unroll
    for (int st = 0; st < 2; ++st) {
        const int qi = q0 + st * 64 + wv * 16 + lr;
        const int qc = qi < 577 ? qi : 576;          // clamp; never stored
        bq[st][0] = *(const half8*)(qh + (size_t)qc * 64 + lq * 8);
        bq[st][1] = *(const half8*)(qh + (size_t)qc * 64 + 32 + lq * 8);
    }

    // prefetch tile kt into buffer pb (4 DMA per thread)
    #define PREF(kt_, pb_)                                               \
        do {                                                             \
            const int j0_ = (kt_) * 64;                                  \
            {   const int c_ = wv * 64 + lane;                           \
                const int r_ = c_ >> 3, cl_ = (c_ & 7) ^ (r_ & 7);       \
                gl_lds16(kh + (size_t)(j0_ + r_) * 64 + cl_ * 8,         \
                         &Ks[pb_][(wv * 64) * 8]);                       \
                gl_lds16(vh + (size_t)r_ * VTS + j0_ + cl_ * 8,          \
                         &Vs[pb_][(wv * 64) * 8]);   }                   \
            {   const int c_ = 256 + wv * 64 + lane;                     \
                const int r_ = c_ >> 3, cl_ = (c_ & 7) ^ (r_ & 7);       \
                gl_lds16(kh + (size_t)(j0_ + r_) * 64 + cl_ * 8,         \
                         &Ks[pb_][(256 + wv * 64) * 8]);                 \
                gl_lds16(vh + (size_t)r_ * VTS + j0_ + cl_ * 8,          \
                         &Vs[pb_][(256 + wv * 64) * 8]);   }             \
        } while (0)

    const floatx4 fz = {0.f, 0.f, 0.f, 0.f};
    floatx4 ot[2][4];
    #pragma unroll
    for (int st = 0; st < 2; ++st)
        #pragma unroll
        for (int c = 0; c < 4; ++c) ot[st][c] = fz;
    float sacc[2] = {0.f, 0.f};

    PREF(0, 0);
    for (int kt = 0; kt < 10; ++kt) {
        const int bf = kt & 1;
        if (kt < 9) {
            PREF(kt + 1, bf ^ 1);
            asm volatile("s_waitcnt vmcnt(4)" ::: "memory");  // tile kt landed; kt+1 in flight
        } else {
            asm volatile("s_waitcnt vmcnt(0)" ::: "memory");
        }
        asm volatile("s_barrier" ::: "memory");

        half8 ak[4][2];
        #pragma unroll
        for (int ct = 0; ct < 4; ++ct) {
            const int base = (ct * 16 + lr) * 64;
            ak[ct][0] = *(const half8*)&Ks[bf][base + xs * 8];
            ak[ct][1] = *(const half8*)&Ks[bf][base + xs4 * 8];
        }

        floatx4 s[2][4];
        #pragma unroll
        for (int st = 0; st < 2; ++st)
            #pragma unroll
            for (int ct = 0; ct < 4; ++ct) {
                floatx4 t = __builtin_amdgcn_mfma_f32_16x16x32_f16(ak[ct][0], bq[st][0], fz, 0, 0, 0);
                s[st][ct] = __builtin_amdgcn_mfma_f32_16x16x32_f16(ak[ct][1], bq[st][1], t, 0, 0, 0);
            }

        if (kt == 9) {
            #pragma unroll
            for (int st = 0; st < 2; ++st) {
                s[st][0][0] = (lq == 0) ? s[st][0][0] : -INFINITY;
                s[st][0][1] = -INFINITY; s[st][0][2] = -INFINITY; s[st][0][3] = -INFINITY;
                #pragma unroll
                for (int ct = 1; ct < 4; ++ct) {
                    s[st][ct][0] = -INFINITY; s[st][ct][1] = -INFINITY;
                    s[st][ct][2] = -INFINITY; s[st][ct][3] = -INFINITY;
                }
            }
        }
        #pragma unroll
        for (int st = 0; st < 2; ++st) {
            if (kt == qt * 2 + st) {
                #pragma unroll
                for (int ct = 0; ct < 4; ++ct)
                    if (ct == wv) {
                        #pragma unroll
                        for (int r = 0; r < 4; ++r)
                            if (lq * 4 + r == lr) s[st][ct][r] = -INFINITY;
                    }
            }
        }

        hv4 pk[2][4];
        #pragma unroll
        for (int st = 0; st < 2; ++st)
            #pragma unroll
            for (int ct = 0; ct < 4; ++ct) {
                const float p0 = __builtin_amdgcn_exp2f(s[st][ct][0]);
                const float p1 = __builtin_amdgcn_exp2f(s[st][ct][1]);
                const float p2 = __builtin_amdgcn_exp2f(s[st][ct][2]);
                const float p3 = __builtin_amdgcn_exp2f(s[st][ct][3]);
                sacc[st] += (p0 + p1) + (p2 + p3);
                const hv2 lo = __builtin_amdgcn_cvt_pkrtz(p0, p1);
                const hv2 hi = __builtin_amdgcn_cvt_pkrtz(p2, p3);
                pk[st][ct] = __builtin_shufflevector(lo, hi, 0, 1, 2, 3);
            }

        #pragma unroll
        for (int jc = 0; jc < 4; ++jc) {
            const int csv = ((jc << 1) | (lq >> 1)) ^ (lr & 7);
            #pragma unroll
            for (int ctd = 0; ctd < 4; ++ctd) {
                const hv4 av = *(const hv4*)&Vs[bf][(ctd * 16 + lr) * 64 + csv * 8 + (lq & 1) * 4];
                #pragma unroll
                for (int st = 0; st < 2; ++st)
                    ot[st][ctd] = __builtin_amdgcn_mfma_f32_16x16x16f16(av, pk[st][jc], ot[st][ctd], 0, 0, 0);
            }
        }

        // WAR: this tile's LDS reads retired before next iter's PREF overwrites
        asm volatile("s_waitcnt lgkmcnt(0)\n\ts_barrier" ::: "memory");
    }
    #undef PREF

    #pragma unroll
    for (int st = 0; st < 2; ++st) {
        float l = sacc[st];
        l += __shfl_xor(l, 16, 64);
        l += __shfl_xor(l, 32, 64);
        const float linv = 1.f / l;
        const int i = q0 + st * 64 + wv * 16 + lr;
        if (i < 577) {
            #pragma unroll
            for (int ctd = 0; ctd < 4; ++ctd) {
                h4f ov;
                #pragma unroll
                for (int r = 0; r < 4; ++r) ov[r] = (_Float16)(ot[st][ctd][r] * linv);
                *(h4f*)(Og + ((size_t)(b * 577 + i)) * 768 + h * 64 + ctd * 16 + lq * 4) = ov;
            }
        }
    }
}

// ---------------- GEMM2: out = O @ W_out + b_out (fp32 out) -----------------
// 128x128/4-wave 2-buffer structure (R7-verified); grid 870, q=108,r=6.
__global__ __launch_bounds__(256, 4) void gemm_out(const _Float16* __restrict__ Og,
                                                   const _Float16* __restrict__ wT,
                                                   const float* __restrict__ bias,
                                                   float* __restrict__ out) {
    __shared__ _Float16 As[2][128 * 32];
    __shared__ _Float16 Bs[2][128 * 32];
    const unsigned orig = blockIdx.x;
    const unsigned xcd = orig & 7u, bidx = orig >> 3;
    const unsigned swz = (xcd < 6u ? xcd * 109u : 654u + (xcd - 6u) * 108u) + bidx;
    const unsigned mi = swz / 6u, ni = swz - mi * 6u;
    const int m0 = (int)mi * 128, n0 = (int)ni * 128;
    const int tid = threadIdx.x;
    const int lane = tid & 63, wv = tid >> 6;
    const int wrow = wv >> 1, wcol = wv & 1;
    const int lr = lane & 15, lq = lane >> 4;

    const int r1 = tid >> 2,        c1 = (((tid & 3) ^ ((r1 >> 1) & 3)) * 8);
    const int r2 = 64 + (tid >> 2), c2 = (((tid & 3) ^ ((r2 >> 1) & 3)) * 8);
    const int xc = (lq ^ ((lr >> 1) & 3)) * 8;

    floatx4 acc[4][4];
    const floatx4 fz = {0.f, 0.f, 0.f, 0.f};
    for (int i = 0; i < 4; ++i)
        for (int j = 0; j < 4; ++j) acc[i][j] = fz;

    #define STAGE_OUT(ki, bfx)                                                      \
        do {                                                                        \
            const int kk_ = (ki) * 32;                                              \
            gl_lds16(Og + (size_t)(m0 + r1) * 768 + kk_ + c1, &As[bfx][wv*64*8]);   \
            gl_lds16(Og + (size_t)(m0 + r2) * 768 + kk_ + c2,                       \
                     &As[bfx][(256 + wv*64) * 8]);                                  \
            gl_lds16(wT + (size_t)(n0 + r1) * 768 + kk_ + c1, &Bs[bfx][wv*64*8]);   \
            gl_lds16(wT + (size_t)(n0 + r2) * 768 + kk_ + c2,                       \
                     &Bs[bfx][(256 + wv*64) * 8]);                                  \
        } while (0)

    STAGE_OUT(0, 0);
    for (int ki = 0; ki < 24; ++ki) {
        const int bf = ki & 1;
        if (ki < 23) {
            STAGE_OUT(ki + 1, bf ^ 1);
            asm volatile("s_waitcnt vmcnt(4)" ::: "memory");
        } else {
            asm volatile("s_waitcnt vmcnt(0)" ::: "memory");
        }
        asm volatile("s_barrier" ::: "memory");

        half8 af[4], bfr[4];
        #pragma unroll
        for (int i = 0; i < 4; ++i)
            af[i] = *(const half8*)&As[bf][(wrow * 64 + i * 16 + lr) * 32 + xc];
        #pragma unroll
        for (int j = 0; j < 4; ++j)
            bfr[j] = *(const half8*)&Bs[bf][(wcol * 64 + j * 16 + lr) * 32 + xc];
        #pragma unroll
        for (int i = 0; i < 4; ++i)
            #pragma unroll
            for (int j = 0; j < 4; ++j)
                acc[i][j] = __builtin_amdgcn_mfma_f32_16x16x32_f16(af[i], bfr[j], acc[i][j], 0, 0, 0);

        asm volatile("s_waitcnt lgkmcnt(0)\n\ts_barrier" ::: "memory");
    }
    #undef STAGE_OUT

    #pragma unroll
    for (int j = 0; j < 4; ++j) {
        const int c = n0 + wcol * 64 + j * 16 + lr;
        const float bv = bias[c];
        #pragma unroll
        for (int i = 0; i < 4; ++i)
            #pragma unroll
            for (int r = 0; r < 4; ++r) {
                const int row = m0 + wrow * 64 + i * 16 + lq * 4 + r;
                if (row < MTOT) out[(size_t)row * 768 + c] = acc[i][j][r] + bv;
            }
    }
}

// ---------------------------------------------------------------------------
extern "C" void kernel_launch(void* const* d_in, const int* in_sizes, int n_in,
                              void* d_out, int out_size, void* d_ws, size_t ws_size,
                              hipStream_t stream) {
    const float* x      = (const float*)d_in[0];   // [32,577,768]
    const float* W_qkv  = (const float*)d_in[1];   // [768,2304]
    const float* scale  = (const float*)d_in[2];   // [12]
    const float* W_out  = (const float*)d_in[3];   // [768,768]
    const float* b_out  = (const float*)d_in[4];   // [768]
    float* out = (float*)d_out;

    // workspace (f16):
    //   Og [18560,768]      28,508,160 B  (slot formerly x16)
    //   q  [32,12,577,64]   28,360,704 B
    //   k  [32,12,577,64]   28,360,704 B
    //   vT [32,12,64,584]   28,704,768 B
    //   WqkvT [2304,768]     3,538,944 B
    //   WoutT [768,768]      1,179,648 B    total ~118.7 MB
    char* ws = (char*)d_ws;
    _Float16* Og    = (_Float16*)(ws);
    _Float16* qg    = (_Float16*)(ws + 28508160u);
    _Float16* kg    = (_Float16*)(ws + 28508160u + 28360704u);
    _Float16* vT    = (_Float16*)(ws + 28508160u + 2u * 28360704u);
    _Float16* WqkvT = (_Float16*)(ws + 28508160u + 2u * 28360704u + 28704768u);
    _Float16* WoutT = WqkvT + (size_t)2304 * 768;

    transpose_both<<<dim3(72, 48), 256, 0, stream>>>(W_qkv, W_out, WqkvT, WoutT);
    gemm_qkv<<<2610, 256, 0, stream>>>(x, WqkvT, scale, qg, kg, vT);
    attn_kernel<<<1920, 256, 0, stream>>>(qg, kg, vT, Og);
    gemm_out<<<870, 256, 0, stream>>>(Og, WoutT, b_out, out);
}

// Round 12
// 341.861 us; speedup vs baseline: 1.2866x; 1.2866x over previous
//
#include <hip/hip_runtime.h>

// ---------------------------------------------------------------------------
// Attention (LSA, ViT-style) for MI355X / gfx950.
// B=32, N=577, DIM=768, H=12, DH=64. f16 MFMA, fp32 accumulate.
// Best-measured composition (R7 kernels + merged weight-transpose launch):
// GEMMs: 128x128 tile, 4 waves, 2-buffer static-index DMA pipeline (vmcnt(4)),
//        conflict-free source-pre-swizzled global_load_lds (BANK_CONFLICT=0
//        verified), XCD-chunked bijective n-fastest grid (FETCH 146->58 MB
//        verified). gemm_qkv verified 130.4 us in this exact form.
// Attn: double-buffered K/V (PREF(kt+1) before compute(kt), vmcnt(4)),
//        no-max exp2 softmax, S^T trick, register P, XCD-chunked grid.
// ---------------------------------------------------------------------------

typedef _Float16 half8  __attribute__((ext_vector_type(8)));
typedef _Float16 h4f    __attribute__((ext_vector_type(4)));
typedef __fp16   hv2    __attribute__((ext_vector_type(2)));
typedef __fp16   hv4    __attribute__((ext_vector_type(4)));
typedef float    floatx4 __attribute__((ext_vector_type(4)));

#define MTOT   18464          // B*N = 32*577
#define NEG_V  (-987654321.0f)
#define VTS    584            // padded row stride for V^T (multiple of 8)

// async 16B global->LDS (LDS dst = wave-uniform base + lane*16B)
__device__ __forceinline__ void gl_lds16(const _Float16* g, _Float16* l) {
    __builtin_amdgcn_global_load_lds(
        (const __attribute__((address_space(1))) unsigned int*)g,
        (__attribute__((address_space(3))) unsigned int*)l,
        16, 0, 0);
}

// ---------------- x fp32 -> f16, padded+zero-filled to 18560 rows -----------
__global__ __launch_bounds__(256) void cvt_x(const float* __restrict__ x,
                                             _Float16* __restrict__ x16) {
    const size_t idx = ((size_t)blockIdx.x * 256 + threadIdx.x) * 8;
    half8 h = {};
    if (idx < (size_t)MTOT * 768) {
        float4 a = *(const float4*)(x + idx);
        float4 b = *(const float4*)(x + idx + 4);
        h[0] = (_Float16)a.x; h[1] = (_Float16)a.y;
        h[2] = (_Float16)a.z; h[3] = (_Float16)a.w;
        h[4] = (_Float16)b.x; h[5] = (_Float16)b.y;
        h[6] = (_Float16)b.z; h[7] = (_Float16)b.w;
    }
    *(half8*)(x16 + idx) = h;
}

// ---------------- prep: both weight transposes in ONE launch ----------------
// src[K=768][Ncol] f32 -> dst[Ncol][768] f16.  grid (72, 48):
//   by <  24 : W_qkv (Ncol=2304), k0 = by*32,      n0 = bx*32  (bx < 72)
//   by >= 24 : W_out (Ncol= 768), k0 = (by-24)*32, n0 = bx*32  (bx < 24)
__global__ __launch_bounds__(256) void transpose_both(const float* __restrict__ Wqkv,
                                                      const float* __restrict__ Wout,
                                                      _Float16* __restrict__ WqkvT,
                                                      _Float16* __restrict__ WoutT) {
    const float* src;
    _Float16* dst;
    int Ncol, k0, n0;
    if (blockIdx.y < 24) {
        src = Wqkv; dst = WqkvT; Ncol = 2304;
        k0 = blockIdx.y * 32; n0 = blockIdx.x * 32;
    } else {
        if (blockIdx.x >= 24) return;            // block-uniform early exit
        src = Wout; dst = WoutT; Ncol = 768;
        k0 = (blockIdx.y - 24) * 32; n0 = blockIdx.x * 32;
    }
    __shared__ float tile[32][33];
    const int tx = threadIdx.x & 31, ty = threadIdx.x >> 5;   // 32 x 8
    for (int i = 0; i < 32; i += 8)
        tile[ty + i][tx] = src[(size_t)(k0 + ty + i) * Ncol + (n0 + tx)];
    __syncthreads();
    for (int i = 0; i < 32; i += 8)
        dst[(size_t)(n0 + ty + i) * 768 + (k0 + tx)] = (_Float16)tile[tx][ty + i];
}

// ---------------- GEMM1: qkv = x16 @ W_qkv^T, scatter to q,k,v^T (f16) ------
// 128x128 tile, 4 waves (2x2 of 64x64), BK=32, 2-buffer DMA pipeline.
// Grid: 2610 blocks flat, XCD-chunked bijective swizzle (q=326,r=2),
// n-fastest (18 n-tiles/row) -> A-panel + W_qkvT L2-resident.
// q outputs pre-multiplied by scale[h]*log2(e) so attention uses exp2.
__global__ __launch_bounds__(256, 4) void gemm_qkv(const _Float16* __restrict__ x16,
                                                   const _Float16* __restrict__ wT,
                                                   const float* __restrict__ scale,
                                                   _Float16* __restrict__ qg,
                                                   _Float16* __restrict__ kg,
                                                   _Float16* __restrict__ vT) {
    __shared__ _Float16 As[2][128 * 32];    // 2 x 8 KB
    __shared__ _Float16 Bs[2][128 * 32];    // 2 x 8 KB   (32 KB total)
    // bijective XCD swizzle: nwg=2610, q=326, r=2
    const unsigned orig = blockIdx.x;
    const unsigned xcd = orig & 7u, bidx = orig >> 3;
    const unsigned swz = (xcd < 2u ? xcd * 327u : 654u + (xcd - 2u) * 326u) + bidx;
    const unsigned mi = swz / 18u, ni = swz - mi * 18u;
    const int m0 = (int)mi * 128, n0 = (int)ni * 128;
    const int tid = threadIdx.x;
    const int lane = tid & 63, wv = tid >> 6;        // 4 waves
    const int wrow = wv >> 1, wcol = wv & 1;         // 2 x 2
    const int lr = lane & 15, lq = lane >> 4;

    // DMA source offsets; chunk column pre-swizzled by row so the (linear)
    // LDS tile holds source chunk (c ^ ((row>>1)&3)) at slot c.
    const int r1 = tid >> 2,        c1 = (((tid & 3) ^ ((r1 >> 1) & 3)) * 8);
    const int r2 = 64 + (tid >> 2), c2 = (((tid & 3) ^ ((r2 >> 1) & 3)) * 8);
    // read-side swizzled chunk: (row>>1)&3 == (lr>>1)&3 for fragment rows
    const int xc = (lq ^ ((lr >> 1) & 3)) * 8;

    floatx4 acc[4][4];
    const floatx4 fz = {0.f, 0.f, 0.f, 0.f};
    for (int i = 0; i < 4; ++i)
        for (int j = 0; j < 4; ++j) acc[i][j] = fz;

    // stage K-slice ki into buffer bfx (4 DMA per thread)
    #define STAGE_QKV(ki, bfx)                                                      \
        do {                                                                        \
            const int kk_ = (ki) * 32;                                              \
            gl_lds16(x16 + (size_t)(m0 + r1) * 768 + kk_ + c1, &As[bfx][wv*64*8]);  \
            gl_lds16(x16 + (size_t)(m0 + r2) * 768 + kk_ + c2,                      \
                     &As[bfx][(256 + wv*64) * 8]);                                  \
            gl_lds16(wT + (size_t)(n0 + r1) * 768 + kk_ + c1, &Bs[bfx][wv*64*8]);   \
            gl_lds16(wT + (size_t)(n0 + r2) * 768 + kk_ + c2,                       \
                     &Bs[bfx][(256 + wv*64) * 8]);                                  \
        } while (0)

    STAGE_QKV(0, 0);
    for (int ki = 0; ki < 24; ++ki) {
        const int bf = ki & 1;
        if (ki < 23) {
            STAGE_QKV(ki + 1, bf ^ 1);
            asm volatile("s_waitcnt vmcnt(4)" ::: "memory");   // iter-k loads done; k+1 in flight
        } else {
            asm volatile("s_waitcnt vmcnt(0)" ::: "memory");
        }
        asm volatile("s_barrier" ::: "memory");

        half8 af[4], bfr[4];
        #pragma unroll
        for (int i = 0; i < 4; ++i)
            af[i] = *(const half8*)&As[bf][(wrow * 64 + i * 16 + lr) * 32 + xc];
        #pragma unroll
        for (int j = 0; j < 4; ++j)
            bfr[j] = *(const half8*)&Bs[bf][(wcol * 64 + j * 16 + lr) * 32 + xc];
        #pragma unroll
        for (int i = 0; i < 4; ++i)
            #pragma unroll
            for (int j = 0; j < 4; ++j)
                acc[i][j] = __builtin_amdgcn_mfma_f32_16x16x32_f16(af[i], bfr[j], acc[i][j], 0, 0, 0);

        // WAR: all waves' ds_reads retired before next iter's DMA overwrites
        asm volatile("s_waitcnt lgkmcnt(0)\n\ts_barrier" ::: "memory");
    }
    #undef STAGE_QKV

    // epilogue: wave-uniform which/h (wave col-base is a multiple of 64)
    const int cbase = n0 + wcol * 64;
    const int which = cbase / 768;                    // 0=q 1=k 2=v
    const int h = (cbase - which * 768) >> 6;         // head (uniform)
    const float qsc = (which == 0) ? scale[h] * 1.4426950408889634f : 1.0f;
    #pragma unroll
    for (int j = 0; j < 4; ++j) {
        const int d = j * 16 + lr;                    // 0..63 within head
        #pragma unroll
        for (int i = 0; i < 4; ++i)
            #pragma unroll
            for (int r = 0; r < 4; ++r) {
                const int row = m0 + wrow * 64 + i * 16 + lq * 4 + r;
                if (row >= MTOT) continue;
                const unsigned bb = (unsigned)row / 577u;
                const unsigned nn = (unsigned)row - bb * 577u;
                const _Float16 val = (_Float16)(acc[i][j][r] * qsc);
                const size_t head = (size_t)(bb * 12 + h);
                if (which == 0)      qg[(head * 577 + nn) * 64 + d] = val;
                else if (which == 1) kg[(head * 577 + nn) * 64 + d] = val;
                else                 vT[(head * 64 + d) * VTS + nn] = val;
            }
    }
}

// ---------------- flash attention: per (b,h,qtile128) block, 4 waves --------
// Flat 1920-block grid, XCD-chunked, qt fastest (head K/V L2-resident).
// K/V double-buffered: PREF(kt+1) issued BEFORE compute(kt); counted vmcnt(4).
__global__ __launch_bounds__(256) void attn_kernel(const _Float16* __restrict__ qg,
                                                   const _Float16* __restrict__ kg,
                                                   const _Float16* __restrict__ vT,
                                                   _Float16* __restrict__ Og) {
    __shared__ __align__(16) _Float16 Ks[2][64 * 64];   // [j][d], swizzled chunks
    __shared__ __align__(16) _Float16 Vs[2][64 * 64];   // [d][j], swizzled chunks
    const unsigned orig = blockIdx.x;                 // 1920 blocks
    const unsigned swz = (orig & 7u) * 240u + (orig >> 3);
    const int qt = (int)(swz % 5u);
    const unsigned hb = swz / 5u;
    const int h = (int)(hb % 12u), b = (int)(hb / 12u);
    const int tid = threadIdx.x, lane = tid & 63, wv = tid >> 6;
    const int lr = lane & 15, lq = lane >> 4;
    const size_t head = (size_t)(b * 12 + h);
    const _Float16* qh = qg + head * 577 * 64;
    const _Float16* kh = kg + head * 577 * 64;
    const _Float16* vh = vT + head * 64 * VTS;
    const int q0 = qt * 128;
    const int xs = lq ^ (lr & 7), xs4 = xs ^ 4;      // swizzled b128 chunks

    half8 bq[2][2];
    #pragma unroll
    for (int st = 0; st < 2; ++st) {
        const int qi = q0 + st * 64 + wv * 16 + lr;
        const int qc = qi < 577 ? qi : 576;          // clamp; never stored
        bq[st][0] = *(const half8*)(qh + (size_t)qc * 64 + lq * 8);
        bq[st][1] = *(const half8*)(qh + (size_t)qc * 64 + 32 + lq * 8);
    }

    // prefetch tile kt into buffer pb (4 DMA per thread)
    #define PREF(kt_, pb_)                                               \
        do {                                                             \
            const int j0_ = (kt_) * 64;                                  \
            {   const int c_ = wv * 64 + lane;                           \
                const int r_ = c_ >> 3, cl_ = (c_ & 7) ^ (r_ & 7);       \
                gl_lds16(kh + (size_t)(j0_ + r_) * 64 + cl_ * 8,         \
                         &Ks[pb_][(wv * 64) * 8]);                       \
                gl_lds16(vh + (size_t)r_ * VTS + j0_ + cl_ * 8,          \
                         &Vs[pb_][(wv * 64) * 8]);   }                   \
            {   const int c_ = 256 + wv * 64 + lane;                     \
                const int r_ = c_ >> 3, cl_ = (c_ & 7) ^ (r_ & 7);       \
                gl_lds16(kh + (size_t)(j0_ + r_) * 64 + cl_ * 8,         \
                         &Ks[pb_][(256 + wv * 64) * 8]);                 \
                gl_lds16(vh + (size_t)r_ * VTS + j0_ + cl_ * 8,          \
                         &Vs[pb_][(256 + wv * 64) * 8]);   }             \
        } while (0)

    const floatx4 fz = {0.f, 0.f, 0.f, 0.f};
    floatx4 ot[2][4];
    #pragma unroll
    for (int st = 0; st < 2; ++st)
        #pragma unroll
        for (int c = 0; c < 4; ++c) ot[st][c] = fz;
    float sacc[2] = {0.f, 0.f};

    PREF(0, 0);
    for (int kt = 0; kt < 10; ++kt) {
        const int bf = kt & 1;
        if (kt < 9) {
            PREF(kt + 1, bf ^ 1);
            asm volatile("s_waitcnt vmcnt(4)" ::: "memory");  // tile kt landed; kt+1 in flight
        } else {
            asm volatile("s_waitcnt vmcnt(0)" ::: "memory");
        }
        asm volatile("s_barrier" ::: "memory");

        half8 ak[4][2];
        #pragma unroll
        for (int ct = 0; ct < 4; ++ct) {
            const int base = (ct * 16 + lr) * 64;
            ak[ct][0] = *(const half8*)&Ks[bf][base + xs * 8];
            ak[ct][1] = *(const half8*)&Ks[bf][base + xs4 * 8];
        }

        floatx4 s[2][4];
        #pragma unroll
        for (int st = 0; st < 2; ++st)
            #pragma unroll
            for (int ct = 0; ct < 4; ++ct) {
                floatx4 t = __builtin_amdgcn_mfma_f32_16x16x32_f16(ak[ct][0], bq[st][0], fz, 0, 0, 0);
                s[st][ct] = __builtin_amdgcn_mfma_f32_16x16x32_f16(ak[ct][1], bq[st][1], t, 0, 0, 0);
            }

        if (kt == 9) {
            #pragma unroll
            for (int st = 0; st < 2; ++st) {
                s[st][0][0] = (lq == 0) ? s[st][0][0] : -INFINITY;
                s[st][0][1] = -INFINITY; s[st][0][2] = -INFINITY; s[st][0][3] = -INFINITY;
                #pragma unroll
                for (int ct = 1; ct < 4; ++ct) {
                    s[st][ct][0] = -INFINITY; s[st][ct][1] = -INFINITY;
                    s[st][ct][2] = -INFINITY; s[st][ct][3] = -INFINITY;
                }
            }
        }
        #pragma unroll
        for (int st = 0; st < 2; ++st) {
            if (kt == qt * 2 + st) {
                #pragma unroll
                for (int ct = 0; ct < 4; ++ct)
                    if (ct == wv) {
                        #pragma unroll
                        for (int r = 0; r < 4; ++r)
                            if (lq * 4 + r == lr) s[st][ct][r] = -INFINITY;
                    }
            }
        }

        hv4 pk[2][4];
        #pragma unroll
        for (int st = 0; st < 2; ++st)
            #pragma unroll
            for (int ct = 0; ct < 4; ++ct) {
                const float p0 = __builtin_amdgcn_exp2f(s[st][ct][0]);
                const float p1 = __builtin_amdgcn_exp2f(s[st][ct][1]);
                const float p2 = __builtin_amdgcn_exp2f(s[st][ct][2]);
                const float p3 = __builtin_amdgcn_exp2f(s[st][ct][3]);
                sacc[st] += (p0 + p1) + (p2 + p3);
                const hv2 lo = __builtin_amdgcn_cvt_pkrtz(p0, p1);
                const hv2 hi = __builtin_amdgcn_cvt_pkrtz(p2, p3);
                pk[st][ct] = __builtin_shufflevector(lo, hi, 0, 1, 2, 3);
            }

        #pragma unroll
        for (int jc = 0; jc < 4; ++jc) {
            const int csv = ((jc << 1) | (lq >> 1)) ^ (lr & 7);
            #pragma unroll
            for (int ctd = 0; ctd < 4; ++ctd) {
                const hv4 av = *(const hv4*)&Vs[bf][(ctd * 16 + lr) * 64 + csv * 8 + (lq & 1) * 4];
                #pragma unroll
                for (int st = 0; st < 2; ++st)
                    ot[st][ctd] = __builtin_amdgcn_mfma_f32_16x16x16f16(av, pk[st][jc], ot[st][ctd], 0, 0, 0);
            }
        }

        // WAR: this tile's LDS reads retired before next iter's PREF overwrites
        asm volatile("s_waitcnt lgkmcnt(0)\n\ts_barrier" ::: "memory");
    }
    #undef PREF

    #pragma unroll
    for (int st = 0; st < 2; ++st) {
        float l = sacc[st];
        l += __shfl_xor(l, 16, 64);
        l += __shfl_xor(l, 32, 64);
        const float linv = 1.f / l;
        const int i = q0 + st * 64 + wv * 16 + lr;
        if (i < 577) {
            #pragma unroll
            for (int ctd = 0; ctd < 4; ++ctd) {
                h4f ov;
                #pragma unroll
                for (int r = 0; r < 4; ++r) ov[r] = (_Float16)(ot[st][ctd][r] * linv);
                *(h4f*)(Og + ((size_t)(b * 577 + i)) * 768 + h * 64 + ctd * 16 + lq * 4) = ov;
            }
        }
    }
}

// ---------------- GEMM2: out = O @ W_out + b_out (fp32 out) -----------------
// 128x128/4-wave 2-buffer structure (R7-verified); grid 870, q=108,r=6.
__global__ __launch_bounds__(256, 4) void gemm_out(const _Float16* __restrict__ Og,
                                                   const _Float16* __restrict__ wT,
                                                   const float* __restrict__ bias,
                                                   float* __restrict__ out) {
    __shared__ _Float16 As[2][128 * 32];
    __shared__ _Float16 Bs[2][128 * 32];
    const unsigned orig = blockIdx.x;
    const unsigned xcd = orig & 7u, bidx = orig >> 3;
    const unsigned swz = (xcd < 6u ? xcd * 109u : 654u + (xcd - 6u) * 108u) + bidx;
    const unsigned mi = swz / 6u, ni = swz - mi * 6u;
    const int m0 = (int)mi * 128, n0 = (int)ni * 128;
    const int tid = threadIdx.x;
    const int lane = tid & 63, wv = tid >> 6;
    const int wrow = wv >> 1, wcol = wv & 1;
    const int lr = lane & 15, lq = lane >> 4;

    const int r1 = tid >> 2,        c1 = (((tid & 3) ^ ((r1 >> 1) & 3)) * 8);
    const int r2 = 64 + (tid >> 2), c2 = (((tid & 3) ^ ((r2 >> 1) & 3)) * 8);
    const int xc = (lq ^ ((lr >> 1) & 3)) * 8;

    floatx4 acc[4][4];
    const floatx4 fz = {0.f, 0.f, 0.f, 0.f};
    for (int i = 0; i < 4; ++i)
        for (int j = 0; j < 4; ++j) acc[i][j] = fz;

    #define STAGE_OUT(ki, bfx)                                                      \
        do {                                                                        \
            const int kk_ = (ki) * 32;                                              \
            gl_lds16(Og + (size_t)(m0 + r1) * 768 + kk_ + c1, &As[bfx][wv*64*8]);   \
            gl_lds16(Og + (size_t)(m0 + r2) * 768 + kk_ + c2,                       \
                     &As[bfx][(256 + wv*64) * 8]);                                  \
            gl_lds16(wT + (size_t)(n0 + r1) * 768 + kk_ + c1, &Bs[bfx][wv*64*8]);   \
            gl_lds16(wT + (size_t)(n0 + r2) * 768 + kk_ + c2,                       \
                     &Bs[bfx][(256 + wv*64) * 8]);                                  \
        } while (0)

    STAGE_OUT(0, 0);
    for (int ki = 0; ki < 24; ++ki) {
        const int bf = ki & 1;
        if (ki < 23) {
            STAGE_OUT(ki + 1, bf ^ 1);
            asm volatile("s_waitcnt vmcnt(4)" ::: "memory");
        } else {
            asm volatile("s_waitcnt vmcnt(0)" ::: "memory");
        }
        asm volatile("s_barrier" ::: "memory");

        half8 af[4], bfr[4];
        #pragma unroll
        for (int i = 0; i < 4; ++i)
            af[i] = *(const half8*)&As[bf][(wrow * 64 + i * 16 + lr) * 32 + xc];
        #pragma unroll
        for (int j = 0; j < 4; ++j)
            bfr[j] = *(const half8*)&Bs[bf][(wcol * 64 + j * 16 + lr) * 32 + xc];
        #pragma unroll
        for (int i = 0; i < 4; ++i)
            #pragma unroll
            for (int j = 0; j < 4; ++j)
                acc[i][j] = __builtin_amdgcn_mfma_f32_16x16x32_f16(af[i], bfr[j], acc[i][j], 0, 0, 0);

        asm volatile("s_waitcnt lgkmcnt(0)\n\ts_barrier" ::: "memory");
    }
    #undef STAGE_OUT

    #pragma unroll
    for (int j = 0; j < 4; ++j) {
        const int c = n0 + wcol * 64 + j * 16 + lr;
        const float bv = bias[c];
        #pragma unroll
        for (int i = 0; i < 4; ++i)
            #pragma unroll
            for (int r = 0; r < 4; ++r) {
                const int row = m0 + wrow * 64 + i * 16 + lq * 4 + r;
                if (row < MTOT) out[(size_t)row * 768 + c] = acc[i][j][r] + bv;
            }
    }
}

// ---------------------------------------------------------------------------
extern "C" void kernel_launch(void* const* d_in, const int* in_sizes, int n_in,
                              void* d_out, int out_size, void* d_ws, size_t ws_size,
                              hipStream_t stream) {
    const float* x      = (const float*)d_in[0];   // [32,577,768]
    const float* W_qkv  = (const float*)d_in[1];   // [768,2304]
    const float* scale  = (const float*)d_in[2];   // [12]
    const float* W_out  = (const float*)d_in[3];   // [768,768]
    const float* b_out  = (const float*)d_in[4];   // [768]
    float* out = (float*)d_out;

    // workspace (f16), Og aliases x16 (x16 dead after gemm_qkv):
    //   x16/Og [18560,768]  28,508,160 B
    //   q  [32,12,577,64]   28,360,704 B
    //   k  [32,12,577,64]   28,360,704 B
    //   vT [32,12,64,584]   28,704,768 B
    //   WqkvT [2304,768]     3,538,944 B
    //   WoutT [768,768]      1,179,648 B    total ~118.7 MB
    char* ws = (char*)d_ws;
    _Float16* x16   = (_Float16*)(ws);
    _Float16* Og    = x16;
    _Float16* qg    = (_Float16*)(ws + 28508160u);
    _Float16* kg    = (_Float16*)(ws + 28508160u + 28360704u);
    _Float16* vT    = (_Float16*)(ws + 28508160u + 2u * 28360704u);
    _Float16* WqkvT = (_Float16*)(ws + 28508160u + 2u * 28360704u + 28704768u);
    _Float16* WoutT = WqkvT + (size_t)2304 * 768;

    cvt_x<<<6960, 256, 0, stream>>>(x, x16);
    transpose_both<<<dim3(72, 48), 256, 0, stream>>>(W_qkv, W_out, WqkvT, WoutT);
    gemm_qkv<<<2610, 256, 0, stream>>>(x16, WqkvT, scale, qg, kg, vT);
    attn_kernel<<<1920, 256, 0, stream>>>(qg, kg, vT, Og);
    gemm_out<<<870, 256, 0, stream>>>(Og, WoutT, b_out, out);
}

// Round 13
// 322.304 us; speedup vs baseline: 1.3647x; 1.0607x over previous
//
#include <hip/hip_runtime.h>

// ---------------------------------------------------------------------------
// Attention (LSA, ViT-style) for MI355X / gfx950.
// B=32, N=577, DIM=768, H=12, DH=64. f16 MFMA, fp32 accumulate.
// 4 launches: prep (x-cvt + both W transposes) -> gemm_qkv -> attn -> gemm_out.
// GEMMs: 128x128 tile, 4 waves, 2-buffer static-index DMA pipeline (vmcnt(4)),
//        conflict-free source-pre-swizzled global_load_lds (BANK_CONFLICT=0
//        verified), XCD-chunked bijective n-fastest grid (FETCH optimal:
//        58-69 MB = A-once + W x8 XCDs, verified).
// gemm_qkv v-epilogue: transpose 128x128 tile through the (dead) 32 KB LDS
//        and store contiguous 16B m-chunks -> fixes vT scalar-store write
//        amplification (WRITE_SIZE 127 MB vs 85 ideal).
// Attn: double-buffered K/V (PREF(kt+1) before compute(kt), vmcnt(4)),
//        no-max exp2 softmax, S^T trick, register P, XCD-chunked grid.
// ---------------------------------------------------------------------------

typedef _Float16 half8  __attribute__((ext_vector_type(8)));
typedef _Float16 h4f    __attribute__((ext_vector_type(4)));
typedef __fp16   hv2    __attribute__((ext_vector_type(2)));
typedef __fp16   hv4    __attribute__((ext_vector_type(4)));
typedef float    floatx4 __attribute__((ext_vector_type(4)));

#define MTOT   18464          // B*N = 32*577
#define NEG_V  (-987654321.0f)
#define VTS    584            // padded row stride for V^T (multiple of 8)

// async 16B global->LDS (LDS dst = wave-uniform base + lane*16B)
__device__ __forceinline__ void gl_lds16(const _Float16* g, _Float16* l) {
    __builtin_amdgcn_global_load_lds(
        (const __attribute__((address_space(1))) unsigned int*)g,
        (__attribute__((address_space(3))) unsigned int*)l,
        16, 0, 0);
}

// ---------------- prep: x fp32->f16 (zero-padded) + BOTH weight transposes --
// grid: flat 10416 blocks of 256.
//   bid <  6960 : cvt_x   (idx = bid*256*8 span of x16)
//   bid >= 6960 : transpose tb = bid-6960: bx = tb%72, by = tb/72 (0..47)
//     by <  24 : W_qkv (Ncol=2304), k0 = by*32,      n0 = bx*32 (bx < 72)
//     by >= 24 : W_out (Ncol= 768), k0 = (by-24)*32, n0 = bx*32 (bx < 24)
__global__ __launch_bounds__(256) void prep(const float* __restrict__ x,
                                            _Float16* __restrict__ x16,
                                            const float* __restrict__ Wqkv,
                                            const float* __restrict__ Wout,
                                            _Float16* __restrict__ WqkvT,
                                            _Float16* __restrict__ WoutT) {
    __shared__ float tile[32][33];
    if (blockIdx.x < 6960u) {
        const size_t idx = ((size_t)blockIdx.x * 256 + threadIdx.x) * 8;
        half8 h = {};
        if (idx < (size_t)MTOT * 768) {
            float4 a = *(const float4*)(x + idx);
            float4 b = *(const float4*)(x + idx + 4);
            h[0] = (_Float16)a.x; h[1] = (_Float16)a.y;
            h[2] = (_Float16)a.z; h[3] = (_Float16)a.w;
            h[4] = (_Float16)b.x; h[5] = (_Float16)b.y;
            h[6] = (_Float16)b.z; h[7] = (_Float16)b.w;
        }
        *(half8*)(x16 + idx) = h;
        return;
    }
    const unsigned tb = blockIdx.x - 6960u;
    const int bx = (int)(tb % 72u), by = (int)(tb / 72u);
    const float* src;
    _Float16* dst;
    int Ncol, k0, n0;
    if (by < 24) {
        src = Wqkv; dst = WqkvT; Ncol = 2304;
        k0 = by * 32; n0 = bx * 32;
    } else {
        if (bx >= 24) return;                    // block-uniform early exit
        src = Wout; dst = WoutT; Ncol = 768;
        k0 = (by - 24) * 32; n0 = bx * 32;
    }
    const int tx = threadIdx.x & 31, ty = threadIdx.x >> 5;   // 32 x 8
    for (int i = 0; i < 32; i += 8)
        tile[ty + i][tx] = src[(size_t)(k0 + ty + i) * Ncol + (n0 + tx)];
    __syncthreads();
    for (int i = 0; i < 32; i += 8)
        dst[(size_t)(n0 + ty + i) * 768 + (k0 + tx)] = (_Float16)tile[tx][ty + i];
}

// ---------------- GEMM1: qkv = x16 @ W_qkv^T, scatter to q,k,v^T (f16) ------
// 128x128 tile, 4 waves (2x2 of 64x64), BK=32, 2-buffer DMA pipeline.
// Grid: 2610 blocks flat, XCD-chunked bijective swizzle (q=326,r=2),
// n-fastest (18 n-tiles/row) -> A-panel + W_qkvT L2-resident.
// q outputs pre-multiplied by scale[h]*log2(e) so attention uses exp2.
// As[0..1] = A buffers, As[2..3] = B buffers (one contiguous 32 KB array so
// the v-epilogue can reuse it as a flat 128x128 transpose buffer).
__global__ __launch_bounds__(256, 4) void gemm_qkv(const _Float16* __restrict__ x16,
                                                   const _Float16* __restrict__ wT,
                                                   const float* __restrict__ scale,
                                                   _Float16* __restrict__ qg,
                                                   _Float16* __restrict__ kg,
                                                   _Float16* __restrict__ vT) {
    __shared__ _Float16 As[4][128 * 32];    // 4 x 8 KB = 32 KB
    // bijective XCD swizzle: nwg=2610, q=326, r=2
    const unsigned orig = blockIdx.x;
    const unsigned xcd = orig & 7u, bidx = orig >> 3;
    const unsigned swz = (xcd < 2u ? xcd * 327u : 654u + (xcd - 2u) * 326u) + bidx;
    const unsigned mi = swz / 18u, ni = swz - mi * 18u;
    const int m0 = (int)mi * 128, n0 = (int)ni * 128;
    const int tid = threadIdx.x;
    const int lane = tid & 63, wv = tid >> 6;        // 4 waves
    const int wrow = wv >> 1, wcol = wv & 1;         // 2 x 2
    const int lr = lane & 15, lq = lane >> 4;

    // DMA source offsets; chunk column pre-swizzled by row so the (linear)
    // LDS tile holds source chunk (c ^ ((row>>1)&3)) at slot c.
    const int r1 = tid >> 2,        c1 = (((tid & 3) ^ ((r1 >> 1) & 3)) * 8);
    const int r2 = 64 + (tid >> 2), c2 = (((tid & 3) ^ ((r2 >> 1) & 3)) * 8);
    // read-side swizzled chunk: (row>>1)&3 == (lr>>1)&3 for fragment rows
    const int xc = (lq ^ ((lr >> 1) & 3)) * 8;

    floatx4 acc[4][4];
    const floatx4 fz = {0.f, 0.f, 0.f, 0.f};
    for (int i = 0; i < 4; ++i)
        for (int j = 0; j < 4; ++j) acc[i][j] = fz;

    // stage K-slice ki into buffer bfx (4 DMA per thread)
    #define STAGE_QKV(ki, bfx)                                                      \
        do {                                                                        \
            const int kk_ = (ki) * 32;                                              \
            gl_lds16(x16 + (size_t)(m0 + r1) * 768 + kk_ + c1, &As[bfx][wv*64*8]);  \
            gl_lds16(x16 + (size_t)(m0 + r2) * 768 + kk_ + c2,                      \
                     &As[bfx][(256 + wv*64) * 8]);                                  \
            gl_lds16(wT + (size_t)(n0 + r1) * 768 + kk_ + c1,                       \
                     &As[2 + (bfx)][wv*64*8]);                                      \
            gl_lds16(wT + (size_t)(n0 + r2) * 768 + kk_ + c2,                       \
                     &As[2 + (bfx)][(256 + wv*64) * 8]);                            \
        } while (0)

    STAGE_QKV(0, 0);
    for (int ki = 0; ki < 24; ++ki) {
        const int bf = ki & 1;
        if (ki < 23) {
            STAGE_QKV(ki + 1, bf ^ 1);
            asm volatile("s_waitcnt vmcnt(4)" ::: "memory");   // iter-k loads done; k+1 in flight
        } else {
            asm volatile("s_waitcnt vmcnt(0)" ::: "memory");
        }
        asm volatile("s_barrier" ::: "memory");

        half8 af[4], bfr[4];
        #pragma unroll
        for (int i = 0; i < 4; ++i)
            af[i] = *(const half8*)&As[bf][(wrow * 64 + i * 16 + lr) * 32 + xc];
        #pragma unroll
        for (int j = 0; j < 4; ++j)
            bfr[j] = *(const half8*)&As[2 + bf][(wcol * 64 + j * 16 + lr) * 32 + xc];
        #pragma unroll
        for (int i = 0; i < 4; ++i)
            #pragma unroll
            for (int j = 0; j < 4; ++j)
                acc[i][j] = __builtin_amdgcn_mfma_f32_16x16x32_f16(af[i], bfr[j], acc[i][j], 0, 0, 0);

        // WAR: all waves' ds_reads retired before next iter's DMA overwrites
        asm volatile("s_waitcnt lgkmcnt(0)\n\ts_barrier" ::: "memory");
    }
    #undef STAGE_QKV

    // epilogue: 'which' is block-uniform (block spans 128 cols; 768 = 6*128)
    const int cbase = n0 + wcol * 64;
    const int which = cbase / 768;                    // 0=q 1=k 2=v

    if (which == 2) {
        // ---- v: transpose 128m x 128d through LDS, coalesced 16B stores ----
        _Float16* ep = &As[0][0];                     // 16384 elems = 32 KB
        #pragma unroll
        for (int j = 0; j < 4; ++j) {
            const int dg = wcol * 64 + j * 16 + lr;   // 0..127 (col within block)
            #pragma unroll
            for (int i = 0; i < 4; ++i)
                #pragma unroll
                for (int r = 0; r < 4; ++r) {
                    const int ml = wrow * 64 + i * 16 + lq * 4 + r;  // 0..127
                    const int col = ((((ml >> 3) ^ (dg & 7)) << 3) | (ml & 7));
                    ep[dg * 128 + col] = (_Float16)acc[i][j][r];
                }
        }
        __syncthreads();
        const int h0 = (n0 - 1536) >> 6;              // head base of block
        const int dg = tid >> 1;                      // 0..127
        const int h = h0 + (dg >> 6);
        _Float16* dstrow = vT + ((size_t)0);          // computed per chunk (bb varies)
        #pragma unroll
        for (int c = 0; c < 8; ++c) {
            const int mc = ((tid & 1) << 3) | c;      // chunk 0..15
            const int m = m0 + (mc << 3);
            if (m >= MTOT) continue;
            half8 v = *(const half8*)&ep[dg * 128 + ((mc ^ (dg & 7)) << 3)];
            const unsigned bb = (unsigned)m / 577u;
            const unsigned nn = (unsigned)m - bb * 577u;
            if (nn <= 569u && m + 7 < MTOT) {
                _Float16* dst = vT + ((size_t)(bb * 12 + h) * 64 + (dg & 63)) * VTS + nn;
                __builtin_memcpy(dst, &v, 16);        // contiguous, any alignment
            } else {
                #pragma unroll
                for (int e = 0; e < 8; ++e) {
                    const int mm = m + e;
                    if (mm >= MTOT) break;
                    const unsigned bbe = (unsigned)mm / 577u;
                    const unsigned nne = (unsigned)mm - bbe * 577u;
                    vT[((size_t)(bbe * 12 + h) * 64 + (dg & 63)) * VTS + nne] = v[e];
                }
            }
        }
        (void)dstrow;
        return;
    }

    // ---- q / k: original (verified) scatter ----
    const int h = (cbase - which * 768) >> 6;         // head (wave-uniform)
    const float qsc = (which == 0) ? scale[h] * 1.4426950408889634f : 1.0f;
    #pragma unroll
    for (int j = 0; j < 4; ++j) {
        const int d = j * 16 + lr;                    // 0..63 within head
        #pragma unroll
        for (int i = 0; i < 4; ++i)
            #pragma unroll
            for (int r = 0; r < 4; ++r) {
                const int row = m0 + wrow * 64 + i * 16 + lq * 4 + r;
                if (row >= MTOT) continue;
                const unsigned bb = (unsigned)row / 577u;
                const unsigned nn = (unsigned)row - bb * 577u;
                const _Float16 val = (_Float16)(acc[i][j][r] * qsc);
                const size_t head = (size_t)(bb * 12 + h);
                if (which == 0)      qg[(head * 577 + nn) * 64 + d] = val;
                else                 kg[(head * 577 + nn) * 64 + d] = val;
            }
    }
}

// ---------------- flash attention: per (b,h,qtile128) block, 4 waves --------
// Flat 1920-block grid, XCD-chunked, qt fastest (head K/V L2-resident).
// K/V double-buffered: PREF(kt+1) issued BEFORE compute(kt); counted vmcnt(4).
__global__ __launch_bounds__(256) void attn_kernel(const _Float16* __restrict__ qg,
                                                   const _Float16* __restrict__ kg,
                                                   const _Float16* __restrict__ vT,
                                                   _Float16* __restrict__ Og) {
    __shared__ __align__(16) _Float16 Ks[2][64 * 64];   // [j][d], swizzled chunks
    __shared__ __align__(16) _Float16 Vs[2][64 * 64];   // [d][j], swizzled chunks
    const unsigned orig = blockIdx.x;                 // 1920 blocks
    const unsigned swz = (orig & 7u) * 240u + (orig >> 3);
    const int qt = (int)(swz % 5u);
    const unsigned hb = swz / 5u;
    const int h = (int)(hb % 12u), b = (int)(hb / 12u);
    const int tid = threadIdx.x, lane = tid & 63, wv = tid >> 6;
    const int lr = lane & 15, lq = lane >> 4;
    const size_t head = (size_t)(b * 12 + h);
    const _Float16* qh = qg + head * 577 * 64;
    const _Float16* kh = kg + head * 577 * 64;
    const _Float16* vh = vT + head * 64 * VTS;
    const int q0 = qt * 128;
    const int xs = lq ^ (lr & 7), xs4 = xs ^ 4;      // swizzled b128 chunks

    half8 bq[2][2];
    #pragma unroll
    for (int st = 0; st < 2; ++st) {
        const int qi = q0 + st * 64 + wv * 16 + lr;
        const int qc = qi < 577 ? qi : 576;          // clamp; never stored
        bq[st][0] = *(const half8*)(qh + (size_t)qc * 64 + lq * 8);
        bq[st][1] = *(const half8*)(qh + (size_t)qc * 64 + 32 + lq * 8);
    }

    // prefetch tile kt into buffer pb (4 DMA per thread)
    #define PREF(kt_, pb_)                                               \
        do {                                                             \
            const int j0_ = (kt_) * 64;                                  \
            {   const int c_ = wv * 64 + lane;                           \
                const int r_ = c_ >> 3, cl_ = (c_ & 7) ^ (r_ & 7);       \
                gl_lds16(kh + (size_t)(j0_ + r_) * 64 + cl_ * 8,         \
                         &Ks[pb_][(wv * 64) * 8]);                       \
                gl_lds16(vh + (size_t)r_ * VTS + j0_ + cl_ * 8,          \
                         &Vs[pb_][(wv * 64) * 8]);   }                   \
            {   const int c_ = 256 + wv * 64 + lane;                     \
                const int r_ = c_ >> 3, cl_ = (c_ & 7) ^ (r_ & 7);       \
                gl_lds16(kh + (size_t)(j0_ + r_) * 64 + cl_ * 8,         \
                         &Ks[pb_][(256 + wv * 64) * 8]);                 \
                gl_lds16(vh + (size_t)r_ * VTS + j0_ + cl_ * 8,          \
                         &Vs[pb_][(256 + wv * 64) * 8]);   }             \
        } while (0)

    const floatx4 fz = {0.f, 0.f, 0.f, 0.f};
    floatx4 ot[2][4];
    #pragma unroll
    for (int st = 0; st < 2; ++st)
        #pragma unroll
        for (int c = 0; c < 4; ++c) ot[st][c] = fz;
    float sacc[2] = {0.f, 0.f};

    PREF(0, 0);
    for (int kt = 0; kt < 10; ++kt) {
        const int bf = kt & 1;
        if (kt < 9) {
            PREF(kt + 1, bf ^ 1);
            asm volatile("s_waitcnt vmcnt(4)" ::: "memory");  // tile kt landed; kt+1 in flight
        } else {
            asm volatile("s_waitcnt vmcnt(0)" ::: "memory");
        }
        asm volatile("s_barrier" ::: "memory");

        half8 ak[4][2];
        #pragma unroll
        for (int ct = 0; ct < 4; ++ct) {
            const int base = (ct * 16 + lr) * 64;
            ak[ct][0] = *(const half8*)&Ks[bf][base + xs * 8];
            ak[ct][1] = *(const half8*)&Ks[bf][base + xs4 * 8];
        }

        floatx4 s[2][4];
        #pragma unroll
        for (int st = 0; st < 2; ++st)
            #pragma unroll
            for (int ct = 0; ct < 4; ++ct) {
                floatx4 t = __builtin_amdgcn_mfma_f32_16x16x32_f16(ak[ct][0], bq[st][0], fz, 0, 0, 0);
                s[st][ct] = __builtin_amdgcn_mfma_f32_16x16x32_f16(ak[ct][1], bq[st][1], t, 0, 0, 0);
            }

        if (kt == 9) {
            #pragma unroll
            for (int st = 0; st < 2; ++st) {
                s[st][0][0] = (lq == 0) ? s[st][0][0] : -INFINITY;
                s[st][0][1] = -INFINITY; s[st][0][2] = -INFINITY; s[st][0][3] = -INFINITY;
                #pragma unroll
                for (int ct = 1; ct < 4; ++ct) {
                    s[st][ct][0] = -INFINITY; s[st][ct][1] = -INFINITY;
                    s[st][ct][2] = -INFINITY; s[st][ct][3] = -INFINITY;
                }
            }
        }
        #pragma unroll
        for (int st = 0; st < 2; ++st) {
            if (kt == qt * 2 + st) {
                #pragma unroll
                for (int ct = 0; ct < 4; ++ct)
                    if (ct == wv) {
                        #pragma unroll
                        for (int r = 0; r < 4; ++r)
                            if (lq * 4 + r == lr) s[st][ct][r] = -INFINITY;
                    }
            }
        }

        hv4 pk[2][4];
        #pragma unroll
        for (int st = 0; st < 2; ++st)
            #pragma unroll
            for (int ct = 0; ct < 4; ++ct) {
                const float p0 = __builtin_amdgcn_exp2f(s[st][ct][0]);
                const float p1 = __builtin_amdgcn_exp2f(s[st][ct][1]);
                const float p2 = __builtin_amdgcn_exp2f(s[st][ct][2]);
                const float p3 = __builtin_amdgcn_exp2f(s[st][ct][3]);
                sacc[st] += (p0 + p1) + (p2 + p3);
                const hv2 lo = __builtin_amdgcn_cvt_pkrtz(p0, p1);
                const hv2 hi = __builtin_amdgcn_cvt_pkrtz(p2, p3);
                pk[st][ct] = __builtin_shufflevector(lo, hi, 0, 1, 2, 3);
            }

        #pragma unroll
        for (int jc = 0; jc < 4; ++jc) {
            const int csv = ((jc << 1) | (lq >> 1)) ^ (lr & 7);
            #pragma unroll
            for (int ctd = 0; ctd < 4; ++ctd) {
                const hv4 av = *(const hv4*)&Vs[bf][(ctd * 16 + lr) * 64 + csv * 8 + (lq & 1) * 4];
                #pragma unroll
                for (int st = 0; st < 2; ++st)
                    ot[st][ctd] = __builtin_amdgcn_mfma_f32_16x16x16f16(av, pk[st][jc], ot[st][ctd], 0, 0, 0);
            }
        }

        // WAR: this tile's LDS reads retired before next iter's PREF overwrites
        asm volatile("s_waitcnt lgkmcnt(0)\n\ts_barrier" ::: "memory");
    }
    #undef PREF

    #pragma unroll
    for (int st = 0; st < 2; ++st) {
        float l = sacc[st];
        l += __shfl_xor(l, 16, 64);
        l += __shfl_xor(l, 32, 64);
        const float linv = 1.f / l;
        const int i = q0 + st * 64 + wv * 16 + lr;
        if (i < 577) {
            #pragma unroll
            for (int ctd = 0; ctd < 4; ++ctd) {
                h4f ov;
                #pragma unroll
                for (int r = 0; r < 4; ++r) ov[r] = (_Float16)(ot[st][ctd][r] * linv);
                *(h4f*)(Og + ((size_t)(b * 577 + i)) * 768 + h * 64 + ctd * 16 + lq * 4) = ov;
            }
        }
    }
}

// ---------------- GEMM2: out = O @ W_out + b_out (fp32 out) -----------------
// 128x128/4-wave 2-buffer structure (R7-verified); grid 870, q=108,r=6.
__global__ __launch_bounds__(256, 4) void gemm_out(const _Float16* __restrict__ Og,
                                                   const _Float16* __restrict__ wT,
                                                   const float* __restrict__ bias,
                                                   float* __restrict__ out) {
    __shared__ _Float16 As[2][128 * 32];
    __shared__ _Float16 Bs[2][128 * 32];
    const unsigned orig = blockIdx.x;
    const unsigned xcd = orig & 7u, bidx = orig >> 3;
    const unsigned swz = (xcd < 6u ? xcd * 109u : 654u + (xcd - 6u) * 108u) + bidx;
    const unsigned mi = swz / 6u, ni = swz - mi * 6u;
    const int m0 = (int)mi * 128, n0 = (int)ni * 128;
    const int tid = threadIdx.x;
    const int lane = tid & 63, wv = tid >> 6;
    const int wrow = wv >> 1, wcol = wv & 1;
    const int lr = lane & 15, lq = lane >> 4;

    const int r1 = tid >> 2,        c1 = (((tid & 3) ^ ((r1 >> 1) & 3)) * 8);
    const int r2 = 64 + (tid >> 2), c2 = (((tid & 3) ^ ((r2 >> 1) & 3)) * 8);
    const int xc = (lq ^ ((lr >> 1) & 3)) * 8;

    floatx4 acc[4][4];
    const floatx4 fz = {0.f, 0.f, 0.f, 0.f};
    for (int i = 0; i < 4; ++i)
        for (int j = 0; j < 4; ++j) acc[i][j] = fz;

    #define STAGE_OUT(ki, bfx)                                                      \
        do {                                                                        \
            const int kk_ = (ki) * 32;                                              \
            gl_lds16(Og + (size_t)(m0 + r1) * 768 + kk_ + c1, &As[bfx][wv*64*8]);   \
            gl_lds16(Og + (size_t)(m0 + r2) * 768 + kk_ + c2,                       \
                     &As[bfx][(256 + wv*64) * 8]);                                  \
            gl_lds16(wT + (size_t)(n0 + r1) * 768 + kk_ + c1, &Bs[bfx][wv*64*8]);   \
            gl_lds16(wT + (size_t)(n0 + r2) * 768 + kk_ + c2,                       \
                     &Bs[bfx][(256 + wv*64) * 8]);                                  \
        } while (0)

    STAGE_OUT(0, 0);
    for (int ki = 0; ki < 24; ++ki) {
        const int bf = ki & 1;
        if (ki < 23) {
            STAGE_OUT(ki + 1, bf ^ 1);
            asm volatile("s_waitcnt vmcnt(4)" ::: "memory");
        } else {
            asm volatile("s_waitcnt vmcnt(0)" ::: "memory");
        }
        asm volatile("s_barrier" ::: "memory");

        half8 af[4], bfr[4];
        #pragma unroll
        for (int i = 0; i < 4; ++i)
            af[i] = *(const half8*)&As[bf][(wrow * 64 + i * 16 + lr) * 32 + xc];
        #pragma unroll
        for (int j = 0; j < 4; ++j)
            bfr[j] = *(const half8*)&Bs[bf][(wcol * 64 + j * 16 + lr) * 32 + xc];
        #pragma unroll
        for (int i = 0; i < 4; ++i)
            #pragma unroll
            for (int j = 0; j < 4; ++j)
                acc[i][j] = __builtin_amdgcn_mfma_f32_16x16x32_f16(af[i], bfr[j], acc[i][j], 0, 0, 0);

        asm volatile("s_waitcnt lgkmcnt(0)\n\ts_barrier" ::: "memory");
    }
    #undef STAGE_OUT

    #pragma unroll
    for (int j = 0; j < 4; ++j) {
        const int c = n0 + wcol * 64 + j * 16 + lr;
        const float bv = bias[c];
        #pragma unroll
        for (int i = 0; i < 4; ++i)
            #pragma unroll
            for (int r = 0; r < 4; ++r) {
                const int row = m0 + wrow * 64 + i * 16 + lq * 4 + r;
                if (row < MTOT) out[(size_t)row * 768 + c] = acc[i][j][r] + bv;
            }
    }
}

// ---------------------------------------------------------------------------
extern "C" void kernel_launch(void* const* d_in, const int* in_sizes, int n_in,
                              void* d_out, int out_size, void* d_ws, size_t ws_size,
                              hipStream_t stream) {
    const float* x      = (const float*)d_in[0];   // [32,577,768]
    const float* W_qkv  = (const float*)d_in[1];   // [768,2304]
    const float* scale  = (const float*)d_in[2];   // [12]
    const float* W_out  = (const float*)d_in[3];   // [768,768]
    const float* b_out  = (const float*)d_in[4];   // [768]
    float* out = (float*)d_out;

    // workspace (f16), Og aliases x16 (x16 dead after gemm_qkv):
    //   x16/Og [18560,768]  28,508,160 B
    //   q  [32,12,577,64]   28,360,704 B
    //   k  [32,12,577,64]   28,360,704 B
    //   vT [32,12,64,584]   28,704,768 B
    //   WqkvT [2304,768]     3,538,944 B
    //   WoutT [768,768]      1,179,648 B    total ~118.7 MB
    char* ws = (char*)d_ws;
    _Float16* x16   = (_Float16*)(ws);
    _Float16* Og    = x16;
    _Float16* qg    = (_Float16*)(ws + 28508160u);
    _Float16* kg    = (_Float16*)(ws + 28508160u + 28360704u);
    _Float16* vT    = (_Float16*)(ws + 28508160u + 2u * 28360704u);
    _Float16* WqkvT = (_Float16*)(ws + 28508160u + 2u * 28360704u + 28704768u);
    _Float16* WoutT = WqkvT + (size_t)2304 * 768;

    prep<<<10416, 256, 0, stream>>>(x, x16, W_qkv, W_out, WqkvT, WoutT);
    gemm_qkv<<<2610, 256, 0, stream>>>(x16, WqkvT, scale, qg, kg, vT);
    attn_kernel<<<1920, 256, 0, stream>>>(qg, kg, vT, Og);
    gemm_out<<<870, 256, 0, stream>>>(Og, WoutT, b_out, out);
}